// Round 10
// baseline (2279.217 us; speedup 1.0000x reference)
//
#include <hip/hip_runtime.h>
#include <hip/hip_bf16.h>
#include <cstdint>
#include <cstddef>

#define NW 30000
#define NE 30000
#define EE 480000
#define HD 512
#define NL 4
#define SLOPE 0.2f
#define LAM 0.5f
#define ROWP 30080  // rows padded to multiple of 128
#define MT 235      // 128-row m-tiles per ROWP matrix
#define WHH ((size_t)HD * HD)

typedef short short8 __attribute__((ext_vector_type(8)));
typedef float f32x4 __attribute__((ext_vector_type(4)));

static __device__ __forceinline__ float lrelu_f(float x){
    return fmaxf(x, 0.f) + SLOPE * fminf(x, 0.f);
}
static __device__ __forceinline__ short f2bf(float f){
    uint32_t u = __builtin_bit_cast(uint32_t, f);
    u += 0x7FFFu + ((u >> 16) & 1u);
    return (short)(u >> 16);
}
static __device__ __forceinline__ float bf2f(short s){
    uint32_t u = ((uint32_t)(uint16_t)s) << 16;
    return __builtin_bit_cast(float, u);
}

typedef const __attribute__((address_space(1))) void* gas_t;
typedef __attribute__((address_space(3))) void* las_t;
static __device__ __forceinline__ void gload16(const void* g, void* l){
    __builtin_amdgcn_global_load_lds((gas_t)g, (las_t)l, 16, 0, 0);
}

// ---------------- CSR build (3 relations per dispatch) ----------------

__global__ void count3_kernel(const int* __restrict__ dn, const int* __restrict__ dr,
                              const int* __restrict__ dc, int* __restrict__ deg){
    int z = blockIdx.y;
    const int* dst = (z == 0) ? dn : ((z == 1) ? dr : dc);
    int e = blockIdx.x * 256 + threadIdx.x;
    if (e < EE) atomicAdd(&deg[z * 30000 + dst[e]], 1);
}

__global__ void scan3_kernel(const int* __restrict__ deg, int* __restrict__ off3){
    const int* dg = deg + blockIdx.x * 30000;
    int* off = off3 + blockIdx.x * (NW + 1);
    int n = 30000;
    __shared__ int tmp[1024];
    int t = threadIdx.x;
    int carry = 0;
    if (t == 0) off[0] = 0;
    for (int base = 0; base < n; base += 1024){
        int v = (base + t < n) ? dg[base + t] : 0;
        tmp[t] = v; __syncthreads();
        for (int d = 1; d < 1024; d <<= 1){
            int add = (t >= d) ? tmp[t - d] : 0;
            __syncthreads();
            tmp[t] += add;
            __syncthreads();
        }
        if (base + t < n) off[base + t + 1] = tmp[t] + carry;
        carry += tmp[1023];
        __syncthreads();
    }
}

__global__ void fill3_kernel(const int* __restrict__ sn, const int* __restrict__ dn,
                             const int* __restrict__ sr, const int* __restrict__ dr,
                             const int* __restrict__ sc, const int* __restrict__ dc,
                             int* __restrict__ cur, const int* __restrict__ off3,
                             int* __restrict__ el3){
    int z = blockIdx.y;
    const int* src = (z == 0) ? sn : ((z == 1) ? sr : sc);
    const int* dst = (z == 0) ? dn : ((z == 1) ? dr : dc);
    const int* off = off3 + z * (NW + 1);
    int* el = el3 + (size_t)z * EE;
    int e = blockIdx.x * 256 + threadIdx.x;
    if (e < EE){
        int d = dst[e];
        int p = atomicAdd(&cur[z * 30000 + d], 1);
        el[off[d] + p] = src[e];
    }
}

// ---------------- weight transpose fp32[K,N] -> bf16[N,Kpad] ----------------

__global__ __launch_bounds__(256)
void transpose_bf_kernel(const float* __restrict__ in, short* __restrict__ out,
                         int K, int N, int Kpad){
    __shared__ float tile[32][33];
    int kbase = blockIdx.y * 32, nbase = blockIdx.x * 32;
    int tx = threadIdx.x & 31, ty = threadIdx.x >> 5;
    #pragma unroll
    for (int r = 0; r < 4; ++r){
        int k = kbase + ty + r * 8;
        float v = 0.f;
        if (k < K) v = in[(size_t)k * N + nbase + tx];
        tile[ty + r * 8][tx] = v;
    }
    __syncthreads();
    #pragma unroll
    for (int r = 0; r < 4; ++r){
        int n = nbase + ty + r * 8;
        int k = kbase + tx;
        if (k < Kpad) out[(size_t)n * Kpad + k] = f2bf(tile[tx][ty + r * 8]);
    }
}

// ---------------- all 21 HxH transposes in one dispatch ----------------

__global__ __launch_bounds__(256)
void transpose_all_kernel(const float* __restrict__ Wln, const float* __restrict__ Wlr,
                          const float* __restrict__ Wlc, const float* __restrict__ Wrc,
                          const float* __restrict__ Wrn, const float* __restrict__ Wrr,
                          const float* __restrict__ Wpost, short* __restrict__ outT){
    __shared__ float tile[32][33];
    int z = blockIdx.z;
    const float* a; const float* b = nullptr;
    if (z < 4) a = Wln + (size_t)z * WHH;
    else if (z < 8) a = Wlr + (size_t)(z - 4) * WHH;
    else if (z < 12) a = Wlc + (size_t)(z - 8) * WHH;
    else if (z < 16) a = Wrc + (size_t)(z - 12) * WHH;
    else if (z < 20){ a = Wrn + (size_t)(z - 16) * WHH; b = Wrr + (size_t)(z - 16) * WHH; }
    else a = Wpost;
    short* outp = outT + (size_t)z * WHH;
    int kbase = blockIdx.y * 32, nbase = blockIdx.x * 32;
    int tx = threadIdx.x & 31, ty = threadIdx.x >> 5;
    #pragma unroll
    for (int r = 0; r < 4; ++r){
        int k = kbase + ty + r * 8;
        float v = a[(size_t)k * HD + nbase + tx];
        if (b) v += b[(size_t)k * HD + nbase + tx];
        tile[ty + r * 8][tx] = v;
    }
    __syncthreads();
    #pragma unroll
    for (int r = 0; r < 4; ++r){
        int n = nbase + ty + r * 8;
        outp[(size_t)n * HD + kbase + tx] = f2bf(tile[tx][ty + r * 8]);
    }
}

__global__ void addf_kernel(const float* __restrict__ a, const float* __restrict__ b,
                            float* __restrict__ o, int n){
    int i = blockIdx.x * 256 + threadIdx.x;
    if (i < n) o[i] = a[i] + b[i];
}

// ---------------- x_window fp32 -> bf16 [ROWP][1952] ----------------

__global__ __launch_bounds__(256)
void conv_xw_kernel(const float* __restrict__ x, short* __restrict__ o){
    int idx = blockIdx.x * 256 + threadIdx.x;
    if (idx >= 30000 * 244) return;
    int row = idx / 244, c8 = idx - row * 244;
    int base = c8 * 8;
    short8 v = {};
    const float* xp = x + (size_t)row * 1949 + base;
    if (base + 8 <= 1949){
        f32x4 a = *(const f32x4*)xp;
        f32x4 bq = *(const f32x4*)(xp + 4);
        #pragma unroll
        for (int j = 0; j < 4; ++j){ v[j] = f2bf(a[j]); v[j + 4] = f2bf(bq[j]); }
    } else {
        #pragma unroll
        for (int j = 0; j < 8; ++j) if (base + j < 1949) v[j] = f2bf(xp[j]);
    }
    *(short8*)(o + (size_t)row * 1952 + base) = v;
}

// ---------------- x_example fp32[30000][100] -> bf16 [ROWP][128] ----------------

__global__ __launch_bounds__(256)
void conv_xe_kernel(const float* __restrict__ x, short* __restrict__ o){
    int idx = blockIdx.x * 256 + threadIdx.x;
    if (idx >= ROWP * 16) return;
    int row = idx >> 4, c8 = idx & 15;
    int base = c8 * 8;
    short8 v = {};
    if (row < 30000){
        const float* xp = x + (size_t)row * 100 + base;
        #pragma unroll
        for (int j = 0; j < 8; ++j) if (base + j < 100) v[j] = f2bf(xp[j]);
    }
    *(short8*)(o + (size_t)row * 128 + base) = v;
}

// ---------------- fused: dual self-GEMM (blocks < ngemm) + 3-relation seg-mean ----------------
// GEMM part: Zw = h_win@Wcb^T', Ze = h_exp@Wrc^T' (bf16 out, no bias/act), 128x128 tile,
// double-buffered (32KB LDS). Seg part: round-7 relation-major, one wave per slot.
// Self-GEMM has no dependency on seg outputs -> rides under the gather's memory time.

__global__ __launch_bounds__(256)
void fused_self_seg_kernel(const short* __restrict__ hw, const short* __restrict__ he,
                           const short* __restrict__ Wcb, const short* __restrict__ Wrc,
                           short* __restrict__ Zw16, short* __restrict__ Ze16,
                           const int* __restrict__ off3, const int* __restrict__ el3,
                           short* __restrict__ aggA, short* __restrict__ aggB,
                           short* __restrict__ aggC, int ngemm){
    __shared__ short lds[16384];   // A: 2 x 4096 at 0; B: 2 x 4096 at 8192
    int t = threadIdx.x;
    if ((int)blockIdx.x < ngemm){
        int logical = blockIdx.x;
        int mtile = logical >> 2, nc = logical & 3;
        int dsel = mtile & 1, ml = mtile >> 1;
        const short* A = dsel ? he : hw;
        const short* B = dsel ? Wrc : Wcb;
        short* C16 = dsel ? Ze16 : Zw16;
        const int row0 = ml * 128, n0 = nc * 128;
        const int wid = t >> 6, lane = t & 63;
        const int wm = (wid >> 1) * 64, wn = (wid & 1) * 64;
        const int lg = lane >> 4, lr = lane & 15;
        f32x4 acc[4][4] = {};
        int rowi[2], ci[2];
        #pragma unroll
        for (int i = 0; i < 2; ++i){
            int sl = i * 256 + t;
            rowi[i] = sl >> 2;
            ci[i] = (sl & 3) ^ ((rowi[i] >> 1) & 3);
        }
        auto stage = [&](int s){
            int k0 = s * 32, bb = s & 1;
            #pragma unroll
            for (int i = 0; i < 2; ++i)
                gload16(A + (size_t)(row0 + rowi[i]) * HD + k0 + ci[i] * 8,
                        &lds[bb * 4096 + (i * 256 + wid * 64) * 8]);
            #pragma unroll
            for (int i = 0; i < 2; ++i)
                gload16(B + (size_t)(n0 + rowi[i]) * HD + k0 + ci[i] * 8,
                        &lds[8192 + bb * 4096 + (i * 256 + wid * 64) * 8]);
        };
        auto compute = [&](int bb){
            const char* baseA = (const char*)(lds + bb * 4096);
            const char* baseB = (const char*)(lds + 8192 + bb * 4096);
            short8 af[4], bfr[4];
            #pragma unroll
            for (int f = 0; f < 4; ++f){
                int rowA = wm + f * 16 + lr;
                af[f] = *(const short8*)(baseA + rowA * 64 + ((lg ^ ((rowA >> 1) & 3)) << 4));
                int rowB = wn + f * 16 + lr;
                bfr[f] = *(const short8*)(baseB + rowB * 64 + ((lg ^ ((rowB >> 1) & 3)) << 4));
            }
            #pragma unroll
            for (int i = 0; i < 4; ++i)
                #pragma unroll
                for (int j = 0; j < 4; ++j)
                    acc[i][j] = __builtin_amdgcn_mfma_f32_16x16x32_bf16(af[i], bfr[j], acc[i][j], 0, 0, 0);
        };
        stage(0);
        for (int s = 0; s < 16; ++s){
            if (s + 1 < 16){
                stage(s + 1);
                asm volatile("s_waitcnt vmcnt(4)" ::: "memory");
            } else {
                asm volatile("s_waitcnt vmcnt(0)" ::: "memory");
            }
            __builtin_amdgcn_s_barrier();
            __builtin_amdgcn_sched_barrier(0);
            compute(s & 1);
            asm volatile("s_waitcnt lgkmcnt(0)" ::: "memory");
            __builtin_amdgcn_sched_barrier(0);
            __builtin_amdgcn_s_barrier();
        }
        #pragma unroll
        for (int i = 0; i < 4; ++i)
            #pragma unroll
            for (int r2 = 0; r2 < 4; ++r2){
                int gr = row0 + wm + i * 16 + lg * 4 + r2;
                #pragma unroll
                for (int j = 0; j < 4; ++j)
                    C16[(size_t)gr * HD + n0 + wn + j * 16 + lr] = f2bf(acc[i][j][r2]);
            }
    } else {
        int slot = (blockIdx.x - ngemm) * 4 + (t >> 6);
        int lane = t & 63;
        if (slot >= 3 * NW) return;
        int seg = slot / NW;
        int dst = slot - seg * NW;
        const short* h = (seg == 0) ? hw : he;
        const int* off = off3 + seg * (NW + 1);
        const int* el = el3 + (size_t)seg * EE;
        short* outp = (seg == 0) ? aggA : ((seg == 1) ? aggB : aggC);
        int s0 = off[dst], s1 = off[dst + 1];
        float acc[8] = {};
        int e = s0;
        for (; e + 8 <= s1; e += 8){
            int idx[8];
            #pragma unroll
            for (int u = 0; u < 8; ++u) idx[u] = el[e + u];
            short8 v[8];
            #pragma unroll
            for (int u = 0; u < 8; ++u) v[u] = *(const short8*)(h + (size_t)idx[u] * HD + lane * 8);
            #pragma unroll
            for (int u = 0; u < 8; ++u)
                #pragma unroll
                for (int j = 0; j < 8; ++j) acc[j] += bf2f(v[u][j]);
        }
        for (; e < s1; ++e){
            short8 v = *(const short8*)(h + (size_t)el[e] * HD + lane * 8);
            #pragma unroll
            for (int j = 0; j < 8; ++j) acc[j] += bf2f(v[j]);
        }
        float inv = (s1 > s0) ? 1.0f / (float)(s1 - s0) : 0.0f;
        short8 o8;
        #pragma unroll
        for (int j = 0; j < 8; ++j) o8[j] = f2bf(acc[j] * inv);
        *(short8*)(outp + (size_t)dst * HD + lane * 8) = o8;
    }
}

// ---------------- routed dual multi-GEMM, 128x128 tile, 2-deep prefetch, bf16 C-in ----------------

template<int DUAL>
__global__ __launch_bounds__(256)
void mgemm2_kernel(
    const short* __restrict__ a00, const short* __restrict__ a01, const short* __restrict__ a02,
    const short* __restrict__ b00, const short* __restrict__ b01, const short* __restrict__ b02,
    const float* __restrict__ bias0, short* __restrict__ c160, float* __restrict__ c320,
    const short* __restrict__ cin0, int np0, int kt0, int act0,
    const short* __restrict__ a10, const short* __restrict__ a11, const short* __restrict__ a12,
    const short* __restrict__ b10, const short* __restrict__ b11, const short* __restrict__ b12,
    const float* __restrict__ bias1, short* __restrict__ c161, float* __restrict__ c321,
    const short* __restrict__ cin1, int np1, int kt1, int act1,
    int mreal){
    __shared__ short lds[24576];          // A: 3 x 4096 shorts at 0; B: 3 x 4096 at 12288

    int nwg = gridDim.x, orig = blockIdx.x;
    int q = nwg >> 3, r = nwg & 7;
    int xcd = orig & 7, lid = orig >> 3;
    int logical = (xcd < r ? xcd * (q + 1) : r * (q + 1) + (xcd - r) * q) + lid;
    int mtile = logical >> 2, nc = logical & 3;
    int dsel, ml;
    if (DUAL){ dsel = mtile & 1; ml = mtile >> 1; } else { dsel = 0; ml = mtile; }

    const short* A0 = dsel ? a10 : a00;
    const short* A1 = dsel ? a11 : a01;
    const short* A2 = dsel ? a12 : a02;
    const short* B0 = dsel ? b10 : b00;
    const short* B1 = dsel ? b11 : b01;
    const short* B2 = dsel ? b12 : b02;
    const float* bias = dsel ? bias1 : bias0;
    short* C16 = dsel ? c161 : c160;
    float* C32 = dsel ? c321 : c320;
    const short* cin = dsel ? cin1 : cin0;
    const int np = dsel ? np1 : np0;
    const int kt = dsel ? kt1 : kt0;
    const int act = dsel ? act1 : act0;

    const int row0 = ml * 128, n0 = nc * 128;
    const int t = threadIdx.x, wid = t >> 6, lane = t & 63;
    const int wm = (wid >> 1) * 64, wn = (wid & 1) * 64;
    const int lg = lane >> 4, lr = lane & 15;
    f32x4 acc[4][4] = {};

    int rowi[2], ci[2];
    #pragma unroll
    for (int i = 0; i < 2; ++i){
        int sl = i * 256 + t;
        rowi[i] = sl >> 2;
        ci[i] = (sl & 3) ^ ((rowi[i] >> 1) & 3);
    }
    const int kpt = kt >> 5;
    const int nsteps = np * kpt;

    const short* Acur = A0;
    const short* Bcur = B0;
    int sk = 0, sp = 0, sbuf = 0;

    auto stage = [&](){
        int k0 = sk * 32;
        #pragma unroll
        for (int i = 0; i < 2; ++i){
            int ao = (row0 + rowi[i]) * kt + k0 + ci[i] * 8;
            gload16(Acur + ao, &lds[sbuf * 4096 + (i * 256 + wid * 64) * 8]);
        }
        #pragma unroll
        for (int i = 0; i < 2; ++i){
            int bo = (n0 + rowi[i]) * kt + k0 + ci[i] * 8;
            gload16(Bcur + bo, &lds[12288 + sbuf * 4096 + (i * 256 + wid * 64) * 8]);
        }
        sbuf = (sbuf == 2) ? 0 : sbuf + 1;
        if (++sk == kpt){
            sk = 0; ++sp;
            Acur = (sp == 1) ? A1 : A2;
            Bcur = (sp == 1) ? B1 : B2;
        }
    };
    auto compute = [&](int cb){
        const char* baseA = (const char*)(lds + cb * 4096);
        const char* baseB = (const char*)(lds + 12288 + cb * 4096);
        short8 af[4], bfr[4];
        #pragma unroll
        for (int f = 0; f < 4; ++f){
            int rowA = wm + f * 16 + lr;
            af[f] = *(const short8*)(baseA + rowA * 64 + ((lg ^ ((rowA >> 1) & 3)) << 4));
            int rowB = wn + f * 16 + lr;
            bfr[f] = *(const short8*)(baseB + rowB * 64 + ((lg ^ ((rowB >> 1) & 3)) << 4));
        }
        #pragma unroll
        for (int i = 0; i < 4; ++i)
            #pragma unroll
            for (int j = 0; j < 4; ++j)
                acc[i][j] = __builtin_amdgcn_mfma_f32_16x16x32_bf16(af[i], bfr[j], acc[i][j], 0, 0, 0);
    };

    stage();                 // step 0
    stage();                 // step 1
    int cbuf = 0;
    for (int s = 0; s < nsteps; ++s){
        if (s + 1 < nsteps){
            asm volatile("s_waitcnt vmcnt(4)" ::: "memory");
        } else {
            asm volatile("s_waitcnt vmcnt(0)" ::: "memory");
        }
        __builtin_amdgcn_s_barrier();
        if (s + 2 < nsteps) stage();
        __builtin_amdgcn_s_setprio(1);
        compute(cbuf);
        __builtin_amdgcn_s_setprio(0);
        cbuf = (cbuf == 2) ? 0 : cbuf + 1;
    }

    float bv[4];
    #pragma unroll
    for (int f = 0; f < 4; ++f) bv[f] = bias ? bias[n0 + wn + f * 16 + lr] : 0.f;
    #pragma unroll
    for (int i = 0; i < 4; ++i){
        #pragma unroll
        for (int r2 = 0; r2 < 4; ++r2){
            int gr = row0 + wm + i * 16 + lg * 4 + r2;
            #pragma unroll
            for (int j = 0; j < 4; ++j){
                int gc = n0 + wn + j * 16 + lr;
                float v = acc[i][j][r2] + bv[j];
                if (cin) v += bf2f(cin[(size_t)gr * HD + gc]);
                if (act == 2) v *= 0.5f;
                if (act) v = lrelu_f(v);
                C16[(size_t)gr * HD + gc] = f2bf(v);
                if (C32 && gr < mreal) C32[(size_t)gr * HD + gc] = v;
            }
        }
    }
}

// ---------------- AF32 fallback (x_window proj only, if ws too small) ----------------

__global__ __launch_bounds__(128)
void mgemm_af32_kernel(const float* __restrict__ A0, const short* __restrict__ B0,
                       short* __restrict__ C16, int M){
    constexpr int KT = 1952, KACT = 1949, KPT = KT / 32, NSTEPS = KPT, N = 512;
    __shared__ short ldsA[2][2048];
    __shared__ short ldsB[2][4096];
    int nwg = gridDim.x;
    int orig = blockIdx.x;
    int q = nwg >> 3, r = nwg & 7;
    int xcd = orig & 7, lid = orig >> 3;
    int logical = (xcd < r ? xcd * (q + 1) : r * (q + 1) + (xcd - r) * q) + lid;
    const int m0 = (logical >> 2) * 64, n0 = (logical & 3) * 128;
    const int t = threadIdx.x, wid = t >> 6, lane = t & 63;
    const int wn = wid * 64;
    const int lg = lane >> 4, lr = lane & 15;
    f32x4 acc[4][4] = {};
    int rowiA[2], ciA[2];
    #pragma unroll
    for (int i = 0; i < 2; ++i){
        int sl = i * 128 + t;
        rowiA[i] = sl >> 2;
        ciA[i] = (sl & 3) ^ ((rowiA[i] >> 1) & 3);
    }
    int rowiB[4], ciB[4];
    #pragma unroll
    for (int i = 0; i < 4; ++i){
        int sl = i * 128 + t;
        rowiB[i] = sl >> 2;
        ciB[i] = (sl & 3) ^ ((rowiB[i] >> 1) & 3);
    }
    f32x4 ra[2][2];
    auto stage_load = [&](int s){
        int k0 = s * 32;
        int bb = s & 1;
        #pragma unroll
        for (int i = 0; i < 2; ++i){
            int gr = m0 + rowiA[i];
            int gk = k0 + ciA[i] * 8;
            ra[i][0] = (f32x4){0,0,0,0};
            ra[i][1] = (f32x4){0,0,0,0};
            if (gr < M){
                const float* ap = A0 + (size_t)gr * KACT + gk;
                if (gk + 8 <= KACT){
                    ra[i][0] = *(const f32x4*)ap;
                    ra[i][1] = *(const f32x4*)(ap + 4);
                } else {
                    #pragma unroll
                    for (int j = 0; j < 8; ++j)
                        if (gk + j < KACT) ra[i][j >> 2][j & 3] = ap[j];
                }
            }
        }
        #pragma unroll
        for (int i = 0; i < 4; ++i)
            gload16(B0 + (size_t)(n0 + rowiB[i]) * KT + k0 + ciB[i] * 8,
                    &ldsB[bb][(i * 128 + wid * 64) * 8]);
    };
    auto stage_writeA = [&](int s){
        int bb = s & 1;
        #pragma unroll
        for (int i = 0; i < 2; ++i){
            short8 v;
            #pragma unroll
            for (int j = 0; j < 8; ++j) v[j] = f2bf(ra[i][j >> 2][j & 3]);
            *(short8*)&ldsA[bb][(i * 128 + t) * 8] = v;
        }
    };
    auto compute = [&](int s){
        int bb = s & 1;
        short8 af[4], bfr[4];
        #pragma unroll
        for (int f = 0; f < 4; ++f){
            int rowA = f * 16 + lr;
            af[f] = *(const short8*)((const char*)&ldsA[bb][0] + rowA * 64 + ((lg ^ ((rowA >> 1) & 3)) << 4));
            int rowB = wn + f * 16 + lr;
            bfr[f] = *(const short8*)((const char*)&ldsB[bb][0] + rowB * 64 + ((lg ^ ((rowB >> 1) & 3)) << 4));
        }
        #pragma unroll
        for (int i = 0; i < 4; ++i)
            #pragma unroll
            for (int j = 0; j < 4; ++j)
                acc[i][j] = __builtin_amdgcn_mfma_f32_16x16x32_bf16(af[i], bfr[j], acc[i][j], 0, 0, 0);
    };
    stage_load(0);
    stage_writeA(0);
    __syncthreads();
    for (int s = 0; s < NSTEPS; ++s){
        if (s + 1 < NSTEPS) stage_load(s + 1);
        compute(s);
        if (s + 1 < NSTEPS) stage_writeA(s + 1);
        __syncthreads();
    }
    #pragma unroll
    for (int i = 0; i < 4; ++i){
        #pragma unroll
        for (int r2 = 0; r2 < 4; ++r2){
            int gr = m0 + i * 16 + lg * 4 + r2;
            if (gr >= M) continue;
            #pragma unroll
            for (int j = 0; j < 4; ++j){
                int gc = n0 + wn + j * 16 + lr;
                C16[(size_t)gr * N + gc] = f2bf(lrelu_f(acc[i][j][r2]));
            }
        }
    }
}

// ---------------- fp32 tiled GEMM (final 512->100 only) ----------------

__global__ __launch_bounds__(256)
void gemm_kernel(const float* __restrict__ A, const float* __restrict__ B,
                 const float* __restrict__ bias, float* __restrict__ C,
                 int M, int N, int K){
    const int BM = 128, BN = 64, BK = 16;
    __shared__ float As[BK][BM];
    __shared__ float Bs[BK][BN];
    int m0 = blockIdx.y * BM, n0 = blockIdx.x * BN;
    int t = threadIdx.x;
    int tx = t & 15, ty = t >> 4;
    float acc[8][4] = {};
    for (int k0 = 0; k0 < K; k0 += BK){
        #pragma unroll
        for (int i = 0; i < 2; ++i){
            int idx = i * 256 + t;
            int row = idx >> 2, kg = idx & 3;
            float4 v = make_float4(0,0,0,0);
            int gr = m0 + row, gk = k0 + kg * 4;
            if (gr < M && gk + 4 <= K)
                v = *reinterpret_cast<const float4*>(A + (size_t)gr * K + gk);
            As[kg*4+0][row] = v.x; As[kg*4+1][row] = v.y;
            As[kg*4+2][row] = v.z; As[kg*4+3][row] = v.w;
        }
        {
            int row = t >> 4, cg = t & 15;
            int gk = k0 + row, col = n0 + cg * 4;
            float4 v = make_float4(0,0,0,0);
            if (gk < K){
                if (col + 4 <= N){
                    v = *reinterpret_cast<const float4*>(B + (size_t)gk * N + col);
                } else {
                    float tp[4] = {0,0,0,0};
                    #pragma unroll
                    for (int j = 0; j < 4; ++j) if (col + j < N) tp[j] = B[(size_t)gk * N + col + j];
                    v = make_float4(tp[0], tp[1], tp[2], tp[3]);
                }
            }
            *reinterpret_cast<float4*>(&Bs[row][cg*4]) = v;
        }
        __syncthreads();
        #pragma unroll
        for (int k = 0; k < BK; ++k){
            float a[8], b[4];
            #pragma unroll
            for (int r = 0; r < 8; ++r) a[r] = As[k][ty*8 + r];
            #pragma unroll
            for (int c = 0; c < 4; ++c) b[c] = Bs[k][tx*4 + c];
            #pragma unroll
            for (int r = 0; r < 8; ++r)
                #pragma unroll
                for (int c = 0; c < 4; ++c)
                    acc[r][c] = fmaf(a[r], b[c], acc[r][c]);
        }
        __syncthreads();
    }
    #pragma unroll
    for (int r = 0; r < 8; ++r){
        int gr = m0 + ty*8 + r;
        if (gr >= M) continue;
        #pragma unroll
        for (int c = 0; c < 4; ++c){
            int gc = n0 + tx*4 + c;
            if (gc >= N) continue;
            C[(size_t)gr * N + gc] = acc[r][c] + bias[gc];
        }
    }
}

// ---------------- pooling (bf16 gather, round-7 non-persistent) ----------------

__global__ void score_kernel(const short* __restrict__ he, const float* __restrict__ w,
                             float* __restrict__ score){
    int row = blockIdx.x * 4 + (threadIdx.x >> 6);
    int lane = threadIdx.x & 63;
    if (row >= NE) return;
    float s = 0.f;
    #pragma unroll
    for (int j = 0; j < 8; ++j){
        int idx = lane + j * 64;
        s += bf2f(he[(size_t)row * HD + idx]) * w[idx];
    }
    #pragma unroll
    for (int off = 32; off > 0; off >>= 1) s += __shfl_down(s, off);
    if (lane == 0) score[row] = s;
}

__global__ __launch_bounds__(256)
void pool_kernel(const short* __restrict__ he, const float* __restrict__ hwf,
                 const float* __restrict__ score, const int* __restrict__ off,
                 const int* __restrict__ elist, float* __restrict__ outp){
    int dst = blockIdx.x * 4 + (threadIdx.x >> 6);
    int lane = threadIdx.x & 63;
    if (dst >= NW) return;
    int s0 = off[dst], s1 = off[dst + 1];
    float m = -INFINITY;
    for (int e = s0 + lane; e < s1; e += 64) m = fmaxf(m, score[elist[e]]);
    #pragma unroll
    for (int o = 1; o < 64; o <<= 1) m = fmaxf(m, __shfl_xor(m, o));
    float z = 0.f;
    for (int e = s0 + lane; e < s1; e += 64) z += expf(score[elist[e]] - m);
    #pragma unroll
    for (int o = 1; o < 64; o <<= 1) z += __shfl_xor(z, o);
    float zinv = 1.0f / fmaxf(z, 1e-12f);

    float acc[8] = {};
    int e = s0;
    for (; e + 4 <= s1; e += 4){
        int idx[4]; float at[4];
        #pragma unroll
        for (int u = 0; u < 4; ++u) idx[u] = elist[e + u];
        #pragma unroll
        for (int u = 0; u < 4; ++u) at[u] = expf(score[idx[u]] - m) * zinv;
        #pragma unroll
        for (int u = 0; u < 4; ++u){
            short8 v = *(const short8*)(he + (size_t)idx[u] * HD + lane * 8);
            #pragma unroll
            for (int k = 0; k < 8; ++k) acc[k] += at[u] * bf2f(v[k]);
        }
    }
    for (; e < s1; ++e){
        int src = elist[e];
        float at = expf(score[src] - m) * zinv;
        short8 v = *(const short8*)(he + (size_t)src * HD + lane * 8);
        #pragma unroll
        for (int k = 0; k < 8; ++k) acc[k] += at * bf2f(v[k]);
    }
    f32x4 h0 = *(const f32x4*)(hwf + (size_t)dst * HD + lane * 8);
    f32x4 h1 = *(const f32x4*)(hwf + (size_t)dst * HD + lane * 8 + 4);
    f32x4 o0, o1;
    #pragma unroll
    for (int k = 0; k < 4; ++k){ o0[k] = h0[k] + LAM * acc[k]; o1[k] = h1[k] + LAM * acc[k+4]; }
    *(f32x4*)(outp + (size_t)dst * HD + lane * 8) = o0;
    *(f32x4*)(outp + (size_t)dst * HD + lane * 8 + 4) = o1;
}

// ---------------- host ----------------

extern "C" void kernel_launch(void* const* d_in, const int* in_sizes, int n_in,
                              void* d_out, int out_size, void* d_ws, size_t ws_size,
                              hipStream_t stream){
    const float* x_window = (const float*)d_in[0];
    const float* x_example= (const float*)d_in[1];
    const int*   e_near   = (const int*)d_in[2];
    const int*   e_close  = (const int*)d_in[3];
    const int*   e_refer  = (const int*)d_in[4];
    const float* W_win    = (const float*)d_in[5];
    const float* W_exp    = (const float*)d_in[6];
    const float* W_post   = (const float*)d_in[7];
    const float* Wl_near  = (const float*)d_in[9];
    const float* Wr_near  = (const float*)d_in[10];
    const float* b_near   = (const float*)d_in[11];
    const float* Wl_close = (const float*)d_in[12];
    const float* Wr_close = (const float*)d_in[13];
    const float* b_close  = (const float*)d_in[14];
    const float* Wl_refer = (const float*)d_in[15];
    const float* Wr_refer = (const float*)d_in[16];
    const float* b_refer  = (const float*)d_in[17];
    const float* w_pool   = (const float*)d_in[18];
    const float* W_lin    = (const float*)d_in[19];
    const float* b_lin    = (const float*)d_in[20];
    float* out = (float*)d_out;
    (void)in_sizes; (void)n_in; (void)out_size;

    char* w = (char*)d_ws;
    size_t o = 0;
    auto alloc = [&](size_t bytes)->char*{
        char* p = w + o;
        o += (bytes + 255) & ~(size_t)255;
        return p;
    };
    const size_t HBH = (size_t)ROWP * HD * 2;

    short* h16[2][2];
    h16[0][0] = (short*)alloc(HBH); h16[0][1] = (short*)alloc(HBH);
    h16[1][0] = (short*)alloc(HBH); h16[1][1] = (short*)alloc(HBH);
    short* aggA = (short*)alloc(HBH);
    short* aggB = (short*)alloc(HBH);
    short* aggC = (short*)alloc(HBH);
    short* Zw16 = (short*)alloc(HBH);
    short* Ze16 = (short*)alloc(HBH);
    float* hwf  = (float*)alloc((size_t)NW * HD * 4);
    float* pooled = (float*)alloc((size_t)NW * HD * 4);
    short* xe16   = (short*)alloc((size_t)ROWP * 128 * 2);
    short* WwinT  = (short*)alloc((size_t)HD * 1952 * 2);
    short* WexpT  = (short*)alloc((size_t)HD * 128 * 2);
    short* WT     = (short*)alloc((size_t)21 * WHH * 2);
    short* WlnT = WT;
    short* WlrT = WT + 4 * WHH;
    short* WlcT = WT + 8 * WHH;
    short* WrcT = WT + 12 * WHH;
    short* WcbT = WT + 16 * WHH;
    short* WpostT = WT + 20 * WHH;
    float* bsum   = (float*)alloc((size_t)NL * HD * 4);
    float* score  = (float*)alloc((size_t)NE * 4);
    int* degcur = (int*)alloc((size_t)6 * 30000 * 4);
    int* deg3 = degcur;
    int* cur3 = degcur + 90000;
    int* off3 = (int*)alloc((size_t)3 * (NW + 1) * 4);
    int* el3  = (int*)alloc((size_t)3 * EE * 4);
    int* off_r = off3 + (NW + 1);

    const size_t XWB = (size_t)ROWP * 1952 * 2;
    bool haveXW16 = false;
    short* xw16 = nullptr;
    size_t rem = (ws_size > o) ? ws_size - o : 0;
    if (rem >= XWB + 256){
        xw16 = (short*)alloc(XWB);
        haveXW16 = true;
    }

    const int* src_n = e_near;  const int* dst_n = e_near + EE;
    const int* src_c = e_close; const int* dst_c = e_close + EE;
    const int* src_r = e_refer; const int* dst_r = e_refer + EE;

    // ---- CSR build ----
    hipMemsetAsync(degcur, 0, (size_t)6 * 30000 * 4, stream);
    int eg = (EE + 255) / 256;
    hipLaunchKernelGGL(count3_kernel, dim3(eg, 3), dim3(256), 0, stream, dst_n, dst_r, dst_c, deg3);
    hipLaunchKernelGGL(scan3_kernel, dim3(3), dim3(1024), 0, stream, deg3, off3);
    hipLaunchKernelGGL(fill3_kernel, dim3(eg, 3), dim3(256), 0, stream,
                       src_n, dst_n, src_r, dst_r, src_c, dst_c, cur3, off3, el3);

    // ---- conversions / transposes ----
    hipLaunchKernelGGL(transpose_bf_kernel, dim3(16, 61, 1), dim3(256), 0, stream,
                       W_win, WwinT, 1949, HD, 1952);
    hipLaunchKernelGGL(transpose_bf_kernel, dim3(16, 4, 1), dim3(256), 0, stream,
                       W_exp, WexpT, 100, HD, 128);
    hipLaunchKernelGGL(transpose_all_kernel, dim3(16, 16, 21), dim3(256), 0, stream,
                       Wl_near, Wl_refer, Wl_close, Wr_close, Wr_near, Wr_refer, W_post, WT);
    hipLaunchKernelGGL(addf_kernel, dim3((NL * HD + 255) / 256), dim3(256), 0, stream,
                       b_near, b_refer, bsum, NL * HD);
    hipLaunchKernelGGL(conv_xe_kernel, dim3((ROWP * 16 + 255) / 256), dim3(256), 0, stream,
                       x_example, xe16);
    if (haveXW16)
        hipLaunchKernelGGL(conv_xw_kernel, dim3((30000 * 244 + 255) / 256), dim3(256), 0, stream,
                           x_window, xw16);

    const short* z16 = xe16;
    const short* zc = nullptr;
    const float* zf = nullptr;

    // ---- feature projections ----
    hipLaunchKernelGGL((mgemm2_kernel<0>), dim3(MT * 4), dim3(256), 0, stream,
        xe16, z16, z16, WexpT, z16, z16, zf, aggA, (float*)nullptr, zc, 1, 128, 1,
        z16, z16, z16, z16, z16, z16, zf, (short*)nullptr, (float*)nullptr, zc, 0, 32, 0, 30000);
    if (haveXW16){
        hipLaunchKernelGGL((mgemm2_kernel<0>), dim3(MT * 4), dim3(256), 0, stream,
            xw16, z16, z16, WwinT, z16, z16, zf, aggB, (float*)nullptr, zc, 1, 1952, 1,
            z16, z16, z16, z16, z16, z16, zf, (short*)nullptr, (float*)nullptr, zc, 0, 32, 0, 30000);
    } else {
        hipLaunchKernelGGL(mgemm_af32_kernel, dim3(4 * ((NW + 63) / 64)), dim3(128), 0, stream,
                           x_window, WwinT, aggB, NW);
    }
    hipLaunchKernelGGL((mgemm2_kernel<1>), dim3(2 * MT * 4), dim3(256), 0, stream,
        aggA, z16, z16, WpostT, z16, z16, zf, h16[1][0], (float*)nullptr, zc, 1, 512, 1,
        aggB, z16, z16, WpostT, z16, z16, zf, h16[0][0], (float*)nullptr, zc, 1, 512, 1, 30000);

    // ---- layers ----
    const int NGEMM = 2 * MT * 4;          // 1880 self-GEMM blocks
    const int NSEG  = (3 * NW + 3) / 4;    // 22500 seg blocks
    for (int l = 0; l < NL; ++l){
        int cur = l & 1, nxt = cur ^ 1;
        const short* wl_n = WlnT + (size_t)l * WHH;
        const short* wl_r = WlrT + (size_t)l * WHH;
        const short* wl_c = WlcT + (size_t)l * WHH;
        const short* wr_c = WrcT + (size_t)l * WHH;
        const short* wcb  = WcbT + (size_t)l * WHH;
        const float* bs   = bsum + (size_t)l * HD;
        const float* bc   = b_close + (size_t)l * HD;
        bool last = (l == NL - 1);

        hipLaunchKernelGGL(fused_self_seg_kernel, dim3(NGEMM + NSEG), dim3(256), 0, stream,
                           h16[0][cur], h16[1][cur], wcb, wr_c, Zw16, Ze16,
                           off3, el3, aggA, aggB, aggC, NGEMM);
        hipLaunchKernelGGL((mgemm2_kernel<1>), dim3(2 * MT * 4), dim3(256), 0, stream,
            aggA, aggB, z16, wl_n, wl_r, z16, bs, h16[0][nxt],
            last ? hwf : (float*)nullptr, Zw16, 2, 512, 2,
            aggC, z16, z16, wl_c, z16, z16, bc, h16[1][nxt],
            (float*)nullptr, Ze16, 1, 512, 1, 30000);
    }
    int fin = NL & 1;

    // ---- CSRA pooling: pooled = hwf + LAM * attn-gather(h_exp bf16) ----
    hipLaunchKernelGGL(score_kernel, dim3((NE + 3) / 4), dim3(256), 0, stream,
                       h16[1][fin], w_pool, score);
    hipLaunchKernelGGL(pool_kernel, dim3((NW + 3) / 4), dim3(256), 0, stream,
                       h16[1][fin], hwf, score, off_r, el3 + (size_t)EE, pooled);

    // ---- final linear (fp32) ----
    hipLaunchKernelGGL(gemm_kernel, dim3(2, (NW + 127) / 128), dim3(256), 0, stream,
                       pooled, W_lin, b_lin, out, NW, 100, HD);
}

// Round 11
// 1764.917 us; speedup vs baseline: 1.2914x; 1.2914x over previous
//
#include <hip/hip_runtime.h>
#include <hip/hip_bf16.h>
#include <cstdint>
#include <cstddef>

#define NW 30000
#define NE 30000
#define EE 480000
#define HD 512
#define NL 4
#define SLOPE 0.2f
#define LAM 0.5f
#define ROWP 30080  // rows padded to multiple of 128
#define MT 235      // 128-row m-tiles per ROWP matrix
#define WHH ((size_t)HD * HD)

typedef short short8 __attribute__((ext_vector_type(8)));
typedef float f32x4 __attribute__((ext_vector_type(4)));

static __device__ __forceinline__ float lrelu_f(float x){
    return fmaxf(x, 0.f) + SLOPE * fminf(x, 0.f);
}
static __device__ __forceinline__ short f2bf(float f){
    uint32_t u = __builtin_bit_cast(uint32_t, f);
    u += 0x7FFFu + ((u >> 16) & 1u);
    return (short)(u >> 16);
}
static __device__ __forceinline__ float bf2f(short s){
    uint32_t u = ((uint32_t)(uint16_t)s) << 16;
    return __builtin_bit_cast(float, u);
}

typedef const __attribute__((address_space(1))) void* gas_t;
typedef __attribute__((address_space(3))) void* las_t;
static __device__ __forceinline__ void gload16(const void* g, void* l){
    __builtin_amdgcn_global_load_lds((gas_t)g, (las_t)l, 16, 0, 0);
}

// ---------------- CSR build (3 relations per dispatch) ----------------

__global__ void count3_kernel(const int* __restrict__ dn, const int* __restrict__ dr,
                              const int* __restrict__ dc, int* __restrict__ deg){
    int z = blockIdx.y;
    const int* dst = (z == 0) ? dn : ((z == 1) ? dr : dc);
    int e = blockIdx.x * 256 + threadIdx.x;
    if (e < EE) atomicAdd(&deg[z * 30000 + dst[e]], 1);
}

__global__ void scan3_kernel(const int* __restrict__ deg, int* __restrict__ off3){
    const int* dg = deg + blockIdx.x * 30000;
    int* off = off3 + blockIdx.x * (NW + 1);
    int n = 30000;
    __shared__ int tmp[1024];
    int t = threadIdx.x;
    int carry = 0;
    if (t == 0) off[0] = 0;
    for (int base = 0; base < n; base += 1024){
        int v = (base + t < n) ? dg[base + t] : 0;
        tmp[t] = v; __syncthreads();
        for (int d = 1; d < 1024; d <<= 1){
            int add = (t >= d) ? tmp[t - d] : 0;
            __syncthreads();
            tmp[t] += add;
            __syncthreads();
        }
        if (base + t < n) off[base + t + 1] = tmp[t] + carry;
        carry += tmp[1023];
        __syncthreads();
    }
}

__global__ void fill3_kernel(const int* __restrict__ sn, const int* __restrict__ dn,
                             const int* __restrict__ sr, const int* __restrict__ dr,
                             const int* __restrict__ sc, const int* __restrict__ dc,
                             int* __restrict__ cur, const int* __restrict__ off3,
                             int* __restrict__ el3){
    int z = blockIdx.y;
    const int* src = (z == 0) ? sn : ((z == 1) ? sr : sc);
    const int* dst = (z == 0) ? dn : ((z == 1) ? dr : dc);
    const int* off = off3 + z * (NW + 1);
    int* el = el3 + (size_t)z * EE;
    int e = blockIdx.x * 256 + threadIdx.x;
    if (e < EE){
        int d = dst[e];
        int p = atomicAdd(&cur[z * 30000 + d], 1);
        el[off[d] + p] = src[e];
    }
}

// ---------------- weight transpose fp32[K,N] -> bf16[N,Kpad] ----------------

__global__ __launch_bounds__(256)
void transpose_bf_kernel(const float* __restrict__ in, short* __restrict__ out,
                         int K, int N, int Kpad){
    __shared__ float tile[32][33];
    int kbase = blockIdx.y * 32, nbase = blockIdx.x * 32;
    int tx = threadIdx.x & 31, ty = threadIdx.x >> 5;
    #pragma unroll
    for (int r = 0; r < 4; ++r){
        int k = kbase + ty + r * 8;
        float v = 0.f;
        if (k < K) v = in[(size_t)k * N + nbase + tx];
        tile[ty + r * 8][tx] = v;
    }
    __syncthreads();
    #pragma unroll
    for (int r = 0; r < 4; ++r){
        int n = nbase + ty + r * 8;
        int k = kbase + tx;
        if (k < Kpad) out[(size_t)n * Kpad + k] = f2bf(tile[tx][ty + r * 8]);
    }
}

// ---------------- all 21 HxH transposes in one dispatch ----------------

__global__ __launch_bounds__(256)
void transpose_all_kernel(const float* __restrict__ Wln, const float* __restrict__ Wlr,
                          const float* __restrict__ Wlc, const float* __restrict__ Wrc,
                          const float* __restrict__ Wrn, const float* __restrict__ Wrr,
                          const float* __restrict__ Wpost, short* __restrict__ outT){
    __shared__ float tile[32][33];
    int z = blockIdx.z;
    const float* a; const float* b = nullptr;
    if (z < 4) a = Wln + (size_t)z * WHH;
    else if (z < 8) a = Wlr + (size_t)(z - 4) * WHH;
    else if (z < 12) a = Wlc + (size_t)(z - 8) * WHH;
    else if (z < 16) a = Wrc + (size_t)(z - 12) * WHH;
    else if (z < 20){ a = Wrn + (size_t)(z - 16) * WHH; b = Wrr + (size_t)(z - 16) * WHH; }
    else a = Wpost;
    short* outp = outT + (size_t)z * WHH;
    int kbase = blockIdx.y * 32, nbase = blockIdx.x * 32;
    int tx = threadIdx.x & 31, ty = threadIdx.x >> 5;
    #pragma unroll
    for (int r = 0; r < 4; ++r){
        int k = kbase + ty + r * 8;
        float v = a[(size_t)k * HD + nbase + tx];
        if (b) v += b[(size_t)k * HD + nbase + tx];
        tile[ty + r * 8][tx] = v;
    }
    __syncthreads();
    #pragma unroll
    for (int r = 0; r < 4; ++r){
        int n = nbase + ty + r * 8;
        outp[(size_t)n * HD + kbase + tx] = f2bf(tile[tx][ty + r * 8]);
    }
}

__global__ void addf_kernel(const float* __restrict__ a, const float* __restrict__ b,
                            float* __restrict__ o, int n){
    int i = blockIdx.x * 256 + threadIdx.x;
    if (i < n) o[i] = a[i] + b[i];
}

// ---------------- x_window fp32 -> bf16 [ROWP][1952] ----------------

__global__ __launch_bounds__(256)
void conv_xw_kernel(const float* __restrict__ x, short* __restrict__ o){
    int idx = blockIdx.x * 256 + threadIdx.x;
    if (idx >= 30000 * 244) return;
    int row = idx / 244, c8 = idx - row * 244;
    int base = c8 * 8;
    short8 v = {};
    const float* xp = x + (size_t)row * 1949 + base;
    if (base + 8 <= 1949){
        f32x4 a = *(const f32x4*)xp;
        f32x4 bq = *(const f32x4*)(xp + 4);
        #pragma unroll
        for (int j = 0; j < 4; ++j){ v[j] = f2bf(a[j]); v[j + 4] = f2bf(bq[j]); }
    } else {
        #pragma unroll
        for (int j = 0; j < 8; ++j) if (base + j < 1949) v[j] = f2bf(xp[j]);
    }
    *(short8*)(o + (size_t)row * 1952 + base) = v;
}

// ---------------- x_example fp32[30000][100] -> bf16 [ROWP][128] ----------------

__global__ __launch_bounds__(256)
void conv_xe_kernel(const float* __restrict__ x, short* __restrict__ o){
    int idx = blockIdx.x * 256 + threadIdx.x;
    if (idx >= ROWP * 16) return;
    int row = idx >> 4, c8 = idx & 15;
    int base = c8 * 8;
    short8 v = {};
    if (row < 30000){
        const float* xp = x + (size_t)row * 100 + base;
        #pragma unroll
        for (int j = 0; j < 8; ++j) if (base + j < 100) v[j] = f2bf(xp[j]);
    }
    *(short8*)(o + (size_t)row * 128 + base) = v;
}

// ---------------- combined 3-relation segment mean (round-7: relation-major) ----------------

__global__ __launch_bounds__(256)
void seg_mean3_kernel(const short* __restrict__ hw, const short* __restrict__ he,
                      const int* __restrict__ off3, const int* __restrict__ el3,
                      short* __restrict__ aggA, short* __restrict__ aggB, short* __restrict__ aggC){
    int slot = blockIdx.x * 4 + (threadIdx.x >> 6);
    int lane = threadIdx.x & 63;
    if (slot >= 3 * NW) return;
    int seg = slot / NW;
    int dst = slot - seg * NW;
    const short* h = (seg == 0) ? hw : he;
    const int* off = off3 + seg * (NW + 1);
    const int* el = el3 + (size_t)seg * EE;
    short* out = (seg == 0) ? aggA : ((seg == 1) ? aggB : aggC);
    int s0 = off[dst], s1 = off[dst + 1];
    float acc[8] = {};
    int e = s0;
    for (; e + 8 <= s1; e += 8){
        int idx[8];
        #pragma unroll
        for (int u = 0; u < 8; ++u) idx[u] = el[e + u];
        short8 v[8];
        #pragma unroll
        for (int u = 0; u < 8; ++u) v[u] = *(const short8*)(h + (size_t)idx[u] * HD + lane * 8);
        #pragma unroll
        for (int u = 0; u < 8; ++u)
            #pragma unroll
            for (int j = 0; j < 8; ++j) acc[j] += bf2f(v[u][j]);
    }
    for (; e < s1; ++e){
        short8 v = *(const short8*)(h + (size_t)el[e] * HD + lane * 8);
        #pragma unroll
        for (int j = 0; j < 8; ++j) acc[j] += bf2f(v[j]);
    }
    float inv = (s1 > s0) ? 1.0f / (float)(s1 - s0) : 0.0f;
    short8 o8;
    #pragma unroll
    for (int j = 0; j < 8; ++j) o8[j] = f2bf(acc[j] * inv);
    *(short8*)(out + (size_t)dst * HD + lane * 8) = o8;
}

// ---------------- routed dual multi-GEMM, 128x128 tile, triple-buffer 1-barrier ----------------
// Per step: stage(s+1) [4 gload16] -> vmcnt(4) -> s_barrier -> compute(s).
// 3 LDS buffers: stage(s+1) writes (s+1)%3 while slowest wave computes (s-1)%3 -> no 2nd barrier.

template<int DUAL>
__global__ __launch_bounds__(256)
void mgemm2_kernel(
    const short* __restrict__ a00, const short* __restrict__ a01, const short* __restrict__ a02,
    const short* __restrict__ b00, const short* __restrict__ b01, const short* __restrict__ b02,
    const float* __restrict__ bias0, short* __restrict__ c160, float* __restrict__ c320,
    int np0, int kt0, int act0,
    const short* __restrict__ a10, const short* __restrict__ a11, const short* __restrict__ a12,
    const short* __restrict__ b10, const short* __restrict__ b11, const short* __restrict__ b12,
    const float* __restrict__ bias1, short* __restrict__ c161, float* __restrict__ c321,
    int np1, int kt1, int act1,
    int mreal){
    __shared__ short lds[24576];          // A: 3 x 4096 shorts at 0; B: 3 x 4096 at 12288

    int nwg = gridDim.x, orig = blockIdx.x;
    int q = nwg >> 3, r = nwg & 7;
    int xcd = orig & 7, lid = orig >> 3;
    int logical = (xcd < r ? xcd * (q + 1) : r * (q + 1) + (xcd - r) * q) + lid;
    int mtile = logical >> 2, nc = logical & 3;
    int dsel, ml;
    if (DUAL){ dsel = mtile & 1; ml = mtile >> 1; } else { dsel = 0; ml = mtile; }

    const short* A0 = dsel ? a10 : a00;
    const short* A1 = dsel ? a11 : a01;
    const short* A2 = dsel ? a12 : a02;
    const short* B0 = dsel ? b10 : b00;
    const short* B1 = dsel ? b11 : b01;
    const short* B2 = dsel ? b12 : b02;
    const float* bias = dsel ? bias1 : bias0;
    short* C16 = dsel ? c161 : c160;
    float* C32 = dsel ? c321 : c320;
    const int np = dsel ? np1 : np0;
    const int kt = dsel ? kt1 : kt0;
    const int act = dsel ? act1 : act0;

    const int row0 = ml * 128, n0 = nc * 128;
    const int t = threadIdx.x, wid = t >> 6, lane = t & 63;
    const int wm = (wid >> 1) * 64, wn = (wid & 1) * 64;
    const int lg = lane >> 4, lr = lane & 15;
    f32x4 acc[4][4] = {};

    int rowi[2], ci[2];
    #pragma unroll
    for (int i = 0; i < 2; ++i){
        int sl = i * 256 + t;
        rowi[i] = sl >> 2;
        ci[i] = (sl & 3) ^ ((rowi[i] >> 1) & 3);
    }
    const int kpt = kt >> 5;
    const int nsteps = np * kpt;

    const short* Acur = A0;
    const short* Bcur = B0;
    int sk = 0, sp = 0, sbuf = 0;

    auto stage = [&](){
        int k0 = sk * 32;
        #pragma unroll
        for (int i = 0; i < 2; ++i){
            int ao = (row0 + rowi[i]) * kt + k0 + ci[i] * 8;
            gload16(Acur + ao, &lds[sbuf * 4096 + (i * 256 + wid * 64) * 8]);
        }
        #pragma unroll
        for (int i = 0; i < 2; ++i){
            int bo = (n0 + rowi[i]) * kt + k0 + ci[i] * 8;
            gload16(Bcur + bo, &lds[12288 + sbuf * 4096 + (i * 256 + wid * 64) * 8]);
        }
        sbuf = (sbuf == 2) ? 0 : sbuf + 1;
        if (++sk == kpt){
            sk = 0; ++sp;
            Acur = (sp == 1) ? A1 : A2;
            Bcur = (sp == 1) ? B1 : B2;
        }
    };
    auto compute = [&](int cb){
        const char* baseA = (const char*)(lds + cb * 4096);
        const char* baseB = (const char*)(lds + 12288 + cb * 4096);
        short8 af[4], bfr[4];
        #pragma unroll
        for (int f = 0; f < 4; ++f){
            int rowA = wm + f * 16 + lr;
            af[f] = *(const short8*)(baseA + rowA * 64 + ((lg ^ ((rowA >> 1) & 3)) << 4));
            int rowB = wn + f * 16 + lr;
            bfr[f] = *(const short8*)(baseB + rowB * 64 + ((lg ^ ((rowB >> 1) & 3)) << 4));
        }
        #pragma unroll
        for (int i = 0; i < 4; ++i)
            #pragma unroll
            for (int j = 0; j < 4; ++j)
                acc[i][j] = __builtin_amdgcn_mfma_f32_16x16x32_bf16(af[i], bfr[j], acc[i][j], 0, 0, 0);
    };

    stage();
    int cbuf = 0;
    for (int s = 0; s < nsteps; ++s){
        if (s + 1 < nsteps){
            stage();
            asm volatile("s_waitcnt vmcnt(4)" ::: "memory");   // step-s loads complete; s+1 in flight
        } else {
            asm volatile("s_waitcnt vmcnt(0)" ::: "memory");
        }
        __builtin_amdgcn_s_barrier();                          // all waves' step-s data in LDS
        __builtin_amdgcn_sched_barrier(0);
        compute(cbuf);
        cbuf = (cbuf == 2) ? 0 : cbuf + 1;
    }

    float bv[4];
    #pragma unroll
    for (int f = 0; f < 4; ++f) bv[f] = bias ? bias[n0 + wn + f * 16 + lr] : 0.f;
    #pragma unroll
    for (int i = 0; i < 4; ++i){
        #pragma unroll
        for (int r2 = 0; r2 < 4; ++r2){
            int gr = row0 + wm + i * 16 + lg * 4 + r2;
            #pragma unroll
            for (int j = 0; j < 4; ++j){
                int gc = n0 + wn + j * 16 + lr;
                float v = acc[i][j][r2] + bv[j];
                if (act == 2) v *= 0.5f;
                if (act) v = lrelu_f(v);
                C16[(size_t)gr * HD + gc] = f2bf(v);
                if (C32 && gr < mreal) C32[(size_t)gr * HD + gc] = v;
            }
        }
    }
}

// ---------------- AF32 fallback (x_window proj only, if ws too small) ----------------

__global__ __launch_bounds__(128)
void mgemm_af32_kernel(const float* __restrict__ A0, const short* __restrict__ B0,
                       short* __restrict__ C16, int M){
    constexpr int KT = 1952, KACT = 1949, KPT = KT / 32, NSTEPS = KPT, N = 512;
    __shared__ short ldsA[2][2048];
    __shared__ short ldsB[2][4096];
    int nwg = gridDim.x;
    int orig = blockIdx.x;
    int q = nwg >> 3, r = nwg & 7;
    int xcd = orig & 7, lid = orig >> 3;
    int logical = (xcd < r ? xcd * (q + 1) : r * (q + 1) + (xcd - r) * q) + lid;
    const int m0 = (logical >> 2) * 64, n0 = (logical & 3) * 128;
    const int t = threadIdx.x, wid = t >> 6, lane = t & 63;
    const int wn = wid * 64;
    const int lg = lane >> 4, lr = lane & 15;
    f32x4 acc[4][4] = {};
    int rowiA[2], ciA[2];
    #pragma unroll
    for (int i = 0; i < 2; ++i){
        int sl = i * 128 + t;
        rowiA[i] = sl >> 2;
        ciA[i] = (sl & 3) ^ ((rowiA[i] >> 1) & 3);
    }
    int rowiB[4], ciB[4];
    #pragma unroll
    for (int i = 0; i < 4; ++i){
        int sl = i * 128 + t;
        rowiB[i] = sl >> 2;
        ciB[i] = (sl & 3) ^ ((rowiB[i] >> 1) & 3);
    }
    f32x4 ra[2][2];
    auto stage_load = [&](int s){
        int k0 = s * 32;
        int bb = s & 1;
        #pragma unroll
        for (int i = 0; i < 2; ++i){
            int gr = m0 + rowiA[i];
            int gk = k0 + ciA[i] * 8;
            ra[i][0] = (f32x4){0,0,0,0};
            ra[i][1] = (f32x4){0,0,0,0};
            if (gr < M){
                const float* ap = A0 + (size_t)gr * KACT + gk;
                if (gk + 8 <= KACT){
                    ra[i][0] = *(const f32x4*)ap;
                    ra[i][1] = *(const f32x4*)(ap + 4);
                } else {
                    #pragma unroll
                    for (int j = 0; j < 8; ++j)
                        if (gk + j < KACT) ra[i][j >> 2][j & 3] = ap[j];
                }
            }
        }
        #pragma unroll
        for (int i = 0; i < 4; ++i)
            gload16(B0 + (size_t)(n0 + rowiB[i]) * KT + k0 + ciB[i] * 8,
                    &ldsB[bb][(i * 128 + wid * 64) * 8]);
    };
    auto stage_writeA = [&](int s){
        int bb = s & 1;
        #pragma unroll
        for (int i = 0; i < 2; ++i){
            short8 v;
            #pragma unroll
            for (int j = 0; j < 8; ++j) v[j] = f2bf(ra[i][j >> 2][j & 3]);
            *(short8*)&ldsA[bb][(i * 128 + t) * 8] = v;
        }
    };
    auto compute = [&](int s){
        int bb = s & 1;
        short8 af[4], bfr[4];
        #pragma unroll
        for (int f = 0; f < 4; ++f){
            int rowA = f * 16 + lr;
            af[f] = *(const short8*)((const char*)&ldsA[bb][0] + rowA * 64 + ((lg ^ ((rowA >> 1) & 3)) << 4));
            int rowB = wn + f * 16 + lr;
            bfr[f] = *(const short8*)((const char*)&ldsB[bb][0] + rowB * 64 + ((lg ^ ((rowB >> 1) & 3)) << 4));
        }
        #pragma unroll
        for (int i = 0; i < 4; ++i)
            #pragma unroll
            for (int j = 0; j < 4; ++j)
                acc[i][j] = __builtin_amdgcn_mfma_f32_16x16x32_bf16(af[i], bfr[j], acc[i][j], 0, 0, 0);
    };
    stage_load(0);
    stage_writeA(0);
    __syncthreads();
    for (int s = 0; s < NSTEPS; ++s){
        if (s + 1 < NSTEPS) stage_load(s + 1);
        compute(s);
        if (s + 1 < NSTEPS) stage_writeA(s + 1);
        __syncthreads();
    }
    #pragma unroll
    for (int i = 0; i < 4; ++i){
        #pragma unroll
        for (int r2 = 0; r2 < 4; ++r2){
            int gr = m0 + i * 16 + lg * 4 + r2;
            if (gr >= M) continue;
            #pragma unroll
            for (int j = 0; j < 4; ++j){
                int gc = n0 + wn + j * 16 + lr;
                C16[(size_t)gr * N + gc] = f2bf(lrelu_f(acc[i][j][r2]));
            }
        }
    }
}

// ---------------- fp32 tiled GEMM (final 512->100 only) ----------------

__global__ __launch_bounds__(256)
void gemm_kernel(const float* __restrict__ A, const float* __restrict__ B,
                 const float* __restrict__ bias, float* __restrict__ C,
                 int M, int N, int K){
    const int BM = 128, BN = 64, BK = 16;
    __shared__ float As[BK][BM];
    __shared__ float Bs[BK][BN];
    int m0 = blockIdx.y * BM, n0 = blockIdx.x * BN;
    int t = threadIdx.x;
    int tx = t & 15, ty = t >> 4;
    float acc[8][4] = {};
    for (int k0 = 0; k0 < K; k0 += BK){
        #pragma unroll
        for (int i = 0; i < 2; ++i){
            int idx = i * 256 + t;
            int row = idx >> 2, kg = idx & 3;
            float4 v = make_float4(0,0,0,0);
            int gr = m0 + row, gk = k0 + kg * 4;
            if (gr < M && gk + 4 <= K)
                v = *reinterpret_cast<const float4*>(A + (size_t)gr * K + gk);
            As[kg*4+0][row] = v.x; As[kg*4+1][row] = v.y;
            As[kg*4+2][row] = v.z; As[kg*4+3][row] = v.w;
        }
        {
            int row = t >> 4, cg = t & 15;
            int gk = k0 + row, col = n0 + cg * 4;
            float4 v = make_float4(0,0,0,0);
            if (gk < K){
                if (col + 4 <= N){
                    v = *reinterpret_cast<const float4*>(B + (size_t)gk * N + col);
                } else {
                    float tp[4] = {0,0,0,0};
                    #pragma unroll
                    for (int j = 0; j < 4; ++j) if (col + j < N) tp[j] = B[(size_t)gk * N + col + j];
                    v = make_float4(tp[0], tp[1], tp[2], tp[3]);
                }
            }
            *reinterpret_cast<float4*>(&Bs[row][cg*4]) = v;
        }
        __syncthreads();
        #pragma unroll
        for (int k = 0; k < BK; ++k){
            float a[8], b[4];
            #pragma unroll
            for (int r = 0; r < 8; ++r) a[r] = As[k][ty*8 + r];
            #pragma unroll
            for (int c = 0; c < 4; ++c) b[c] = Bs[k][tx*4 + c];
            #pragma unroll
            for (int r = 0; r < 8; ++r)
                #pragma unroll
                for (int c = 0; c < 4; ++c)
                    acc[r][c] = fmaf(a[r], b[c], acc[r][c]);
        }
        __syncthreads();
    }
    #pragma unroll
    for (int r = 0; r < 8; ++r){
        int gr = m0 + ty*8 + r;
        if (gr >= M) continue;
        #pragma unroll
        for (int c = 0; c < 4; ++c){
            int gc = n0 + tx*4 + c;
            if (gc >= N) continue;
            C[(size_t)gr * N + gc] = acc[r][c] + bias[gc];
        }
    }
}

// ---------------- pooling (bf16 gather) ----------------

__global__ void score_kernel(const short* __restrict__ he, const float* __restrict__ w,
                             float* __restrict__ score){
    int row = blockIdx.x * 4 + (threadIdx.x >> 6);
    int lane = threadIdx.x & 63;
    if (row >= NE) return;
    float s = 0.f;
    #pragma unroll
    for (int j = 0; j < 8; ++j){
        int idx = lane + j * 64;
        s += bf2f(he[(size_t)row * HD + idx]) * w[idx];
    }
    #pragma unroll
    for (int off = 32; off > 0; off >>= 1) s += __shfl_down(s, off);
    if (lane == 0) score[row] = s;
}

__global__ __launch_bounds__(256)
void pool_kernel(const short* __restrict__ he, const float* __restrict__ hwf,
                 const float* __restrict__ score, const int* __restrict__ off,
                 const int* __restrict__ elist, float* __restrict__ outp){
    int dst = blockIdx.x * 4 + (threadIdx.x >> 6);
    int lane = threadIdx.x & 63;
    if (dst >= NW) return;
    int s0 = off[dst], s1 = off[dst + 1];
    float m = -INFINITY;
    for (int e = s0 + lane; e < s1; e += 64) m = fmaxf(m, score[elist[e]]);
    #pragma unroll
    for (int o = 1; o < 64; o <<= 1) m = fmaxf(m, __shfl_xor(m, o));
    float z = 0.f;
    for (int e = s0 + lane; e < s1; e += 64) z += expf(score[elist[e]] - m);
    #pragma unroll
    for (int o = 1; o < 64; o <<= 1) z += __shfl_xor(z, o);
    float zinv = 1.0f / fmaxf(z, 1e-12f);

    float acc[8] = {};
    int e = s0;
    for (; e + 4 <= s1; e += 4){
        int idx[4]; float at[4];
        #pragma unroll
        for (int u = 0; u < 4; ++u) idx[u] = elist[e + u];
        #pragma unroll
        for (int u = 0; u < 4; ++u) at[u] = expf(score[idx[u]] - m) * zinv;
        #pragma unroll
        for (int u = 0; u < 4; ++u){
            short8 v = *(const short8*)(he + (size_t)idx[u] * HD + lane * 8);
            #pragma unroll
            for (int k = 0; k < 8; ++k) acc[k] += at[u] * bf2f(v[k]);
        }
    }
    for (; e < s1; ++e){
        int src = elist[e];
        float at = expf(score[src] - m) * zinv;
        short8 v = *(const short8*)(he + (size_t)src * HD + lane * 8);
        #pragma unroll
        for (int k = 0; k < 8; ++k) acc[k] += at * bf2f(v[k]);
    }
    f32x4 h0 = *(const f32x4*)(hwf + (size_t)dst * HD + lane * 8);
    f32x4 h1 = *(const f32x4*)(hwf + (size_t)dst * HD + lane * 8 + 4);
    f32x4 o0, o1;
    #pragma unroll
    for (int k = 0; k < 4; ++k){ o0[k] = h0[k] + LAM * acc[k]; o1[k] = h1[k] + LAM * acc[k+4]; }
    *(f32x4*)(outp + (size_t)dst * HD + lane * 8) = o0;
    *(f32x4*)(outp + (size_t)dst * HD + lane * 8 + 4) = o1;
}

// ---------------- host ----------------

extern "C" void kernel_launch(void* const* d_in, const int* in_sizes, int n_in,
                              void* d_out, int out_size, void* d_ws, size_t ws_size,
                              hipStream_t stream){
    const float* x_window = (const float*)d_in[0];
    const float* x_example= (const float*)d_in[1];
    const int*   e_near   = (const int*)d_in[2];
    const int*   e_close  = (const int*)d_in[3];
    const int*   e_refer  = (const int*)d_in[4];
    const float* W_win    = (const float*)d_in[5];
    const float* W_exp    = (const float*)d_in[6];
    const float* W_post   = (const float*)d_in[7];
    const float* Wl_near  = (const float*)d_in[9];
    const float* Wr_near  = (const float*)d_in[10];
    const float* b_near   = (const float*)d_in[11];
    const float* Wl_close = (const float*)d_in[12];
    const float* Wr_close = (const float*)d_in[13];
    const float* b_close  = (const float*)d_in[14];
    const float* Wl_refer = (const float*)d_in[15];
    const float* Wr_refer = (const float*)d_in[16];
    const float* b_refer  = (const float*)d_in[17];
    const float* w_pool   = (const float*)d_in[18];
    const float* W_lin    = (const float*)d_in[19];
    const float* b_lin    = (const float*)d_in[20];
    float* out = (float*)d_out;
    (void)in_sizes; (void)n_in; (void)out_size;

    char* w = (char*)d_ws;
    size_t o = 0;
    auto alloc = [&](size_t bytes)->char*{
        char* p = w + o;
        o += (bytes + 255) & ~(size_t)255;
        return p;
    };
    const size_t HBH = (size_t)ROWP * HD * 2;

    short* h16[2][2];
    h16[0][0] = (short*)alloc(HBH); h16[0][1] = (short*)alloc(HBH);
    h16[1][0] = (short*)alloc(HBH); h16[1][1] = (short*)alloc(HBH);
    short* aggA = (short*)alloc(HBH);
    short* aggB = (short*)alloc(HBH);
    short* aggC = (short*)alloc(HBH);
    float* hwf  = (float*)alloc((size_t)NW * HD * 4);
    float* pooled = (float*)alloc((size_t)NW * HD * 4);
    short* xe16   = (short*)alloc((size_t)ROWP * 128 * 2);
    short* WwinT  = (short*)alloc((size_t)HD * 1952 * 2);
    short* WexpT  = (short*)alloc((size_t)HD * 128 * 2);
    short* WT     = (short*)alloc((size_t)21 * WHH * 2);
    short* WlnT = WT;
    short* WlrT = WT + 4 * WHH;
    short* WlcT = WT + 8 * WHH;
    short* WrcT = WT + 12 * WHH;
    short* WcbT = WT + 16 * WHH;
    short* WpostT = WT + 20 * WHH;
    float* bsum   = (float*)alloc((size_t)NL * HD * 4);
    float* score  = (float*)alloc((size_t)NE * 4);
    int* degcur = (int*)alloc((size_t)6 * 30000 * 4);
    int* deg3 = degcur;
    int* cur3 = degcur + 90000;
    int* off3 = (int*)alloc((size_t)3 * (NW + 1) * 4);
    int* el3  = (int*)alloc((size_t)3 * EE * 4);
    int* off_r = off3 + (NW + 1);

    const size_t XWB = (size_t)ROWP * 1952 * 2;
    bool haveXW16 = false;
    short* xw16 = nullptr;
    size_t rem = (ws_size > o) ? ws_size - o : 0;
    if (rem >= XWB + 256){
        xw16 = (short*)alloc(XWB);
        haveXW16 = true;
    }

    const int* src_n = e_near;  const int* dst_n = e_near + EE;
    const int* src_c = e_close; const int* dst_c = e_close + EE;
    const int* src_r = e_refer; const int* dst_r = e_refer + EE;

    // ---- CSR build ----
    hipMemsetAsync(degcur, 0, (size_t)6 * 30000 * 4, stream);
    int eg = (EE + 255) / 256;
    hipLaunchKernelGGL(count3_kernel, dim3(eg, 3), dim3(256), 0, stream, dst_n, dst_r, dst_c, deg3);
    hipLaunchKernelGGL(scan3_kernel, dim3(3), dim3(1024), 0, stream, deg3, off3);
    hipLaunchKernelGGL(fill3_kernel, dim3(eg, 3), dim3(256), 0, stream,
                       src_n, dst_n, src_r, dst_r, src_c, dst_c, cur3, off3, el3);

    // ---- conversions / transposes ----
    hipLaunchKernelGGL(transpose_bf_kernel, dim3(16, 61, 1), dim3(256), 0, stream,
                       W_win, WwinT, 1949, HD, 1952);
    hipLaunchKernelGGL(transpose_bf_kernel, dim3(16, 4, 1), dim3(256), 0, stream,
                       W_exp, WexpT, 100, HD, 128);
    hipLaunchKernelGGL(transpose_all_kernel, dim3(16, 16, 21), dim3(256), 0, stream,
                       Wl_near, Wl_refer, Wl_close, Wr_close, Wr_near, Wr_refer, W_post, WT);
    hipLaunchKernelGGL(addf_kernel, dim3((NL * HD + 255) / 256), dim3(256), 0, stream,
                       b_near, b_refer, bsum, NL * HD);
    hipLaunchKernelGGL(conv_xe_kernel, dim3((ROWP * 16 + 255) / 256), dim3(256), 0, stream,
                       x_example, xe16);
    if (haveXW16)
        hipLaunchKernelGGL(conv_xw_kernel, dim3((30000 * 244 + 255) / 256), dim3(256), 0, stream,
                           x_window, xw16);

    const short* z16 = xe16;
    const float* zf = nullptr;

    // ---- feature projections ----
    hipLaunchKernelGGL((mgemm2_kernel<0>), dim3(MT * 4), dim3(256), 0, stream,
        xe16, z16, z16, WexpT, z16, z16, zf, aggA, (float*)nullptr, 1, 128, 1,
        z16, z16, z16, z16, z16, z16, zf, (short*)nullptr, (float*)nullptr, 0, 32, 0, 30000);
    if (haveXW16){
        hipLaunchKernelGGL((mgemm2_kernel<0>), dim3(MT * 4), dim3(256), 0, stream,
            xw16, z16, z16, WwinT, z16, z16, zf, aggB, (float*)nullptr, 1, 1952, 1,
            z16, z16, z16, z16, z16, z16, zf, (short*)nullptr, (float*)nullptr, 0, 32, 0, 30000);
    } else {
        hipLaunchKernelGGL(mgemm_af32_kernel, dim3(4 * ((NW + 63) / 64)), dim3(128), 0, stream,
                           x_window, WwinT, aggB, NW);
    }
    hipLaunchKernelGGL((mgemm2_kernel<1>), dim3(2 * MT * 4), dim3(256), 0, stream,
        aggA, z16, z16, WpostT, z16, z16, zf, h16[1][0], (float*)nullptr, 1, 512, 1,
        aggB, z16, z16, WpostT, z16, z16, zf, h16[0][0], (float*)nullptr, 1, 512, 1, 30000);

    // ---- layers ----
    for (int l = 0; l < NL; ++l){
        int cur = l & 1, nxt = cur ^ 1;
        const short* wl_n = WlnT + (size_t)l * WHH;
        const short* wl_r = WlrT + (size_t)l * WHH;
        const short* wl_c = WlcT + (size_t)l * WHH;
        const short* wr_c = WrcT + (size_t)l * WHH;
        const short* wcb  = WcbT + (size_t)l * WHH;
        const float* bs   = bsum + (size_t)l * HD;
        const float* bc   = b_close + (size_t)l * HD;
        bool last = (l == NL - 1);

        hipLaunchKernelGGL(seg_mean3_kernel, dim3((3 * NW + 3) / 4), dim3(256), 0, stream,
                           h16[0][cur], h16[1][cur], off3, el3, aggA, aggB, aggC);
        hipLaunchKernelGGL((mgemm2_kernel<1>), dim3(2 * MT * 4), dim3(256), 0, stream,
            aggA, aggB, h16[0][cur], wl_n, wl_r, wcb, bs, h16[0][nxt],
            last ? hwf : (float*)nullptr, 3, 512, 2,
            aggC, h16[1][cur], z16, wl_c, wr_c, z16, bc, h16[1][nxt],
            (float*)nullptr, 2, 512, 1, 30000);
    }
    int fin = NL & 1;

    // ---- CSRA pooling: pooled = hwf + LAM * attn-gather(h_exp bf16) ----
    hipLaunchKernelGGL(score_kernel, dim3((NE + 3) / 4), dim3(256), 0, stream,
                       h16[1][fin], w_pool, score);
    hipLaunchKernelGGL(pool_kernel, dim3((NW + 3) / 4), dim3(256), 0, stream,
                       h16[1][fin], hwf, score, off_r, el3 + (size_t)EE, pooled);

    // ---- final linear (fp32) ----
    hipLaunchKernelGGL(gemm_kernel, dim3(2, (NW + 127) / 128), dim3(256), 0, stream,
                       pooled, W_lin, b_lin, out, NW, 100, HD);
}